// Round 2
// baseline (165.935 us; speedup 1.0000x reference)
//
#include <hip/hip_runtime.h>

// VectorQuantizer gather: out[b][d][n] = embedding[indices[b][n]][d]
// B=32, N=4096, K=1024, D=256, fp32 out = 128 MiB  ->  write-BW bound (~21us floor).
//
// R1 lesson: per-lane float4 global gathers (64 distinct lines/instr) serialize in
// TA/L1 (~8.4M line requests) and stall store issue -> only ~2 TB/s effective.
//
// R2 design: gather from LDS, not global.
//  - Block owns (b, 16-wide d-chunk). Stage emb[:, d0:d0+16] = 1024x16 fp32 = 64 KiB
//    into static LDS with a dense, coalesced read (no gather at all).
//  - XOR-swizzled LDS layout: float index (r<<4) + (((r>>1) ^ dl) & 15).
//    Read phase (dl fixed per wave): bank = 16*(id&1) + ((id>>1)^dl)&15, a bijection
//    of id mod 32 -> random idx spreads over all 32 banks, ~2 lanes/bank = free.
//    Write phase: algebra gives exactly 2 lanes/bank = free.
//  - Compute: wave w handles d = d0+w; its store stream is ONE full 16 KiB out row,
//    written sequentially as 16 x (64 lanes x float4 = 1 KiB) dwordx4 stores.
//  - idx loaded as int4 (16B/lane, coalesced, L1-resident 16 KiB/block) per chunk.
//  - 512 blocks x 1024 threads; 64 KiB LDS -> 2 blocks/CU -> 32 waves/CU (max).
//    __launch_bounds__(1024, 8): 8 waves/EU -> VGPR capped at 64 (loop state ~25).

#define VQ_B 32
#define VQ_N 4096
#define VQ_D 256
#define DC   16      // d-columns per block (LDS slice width)

__device__ __forceinline__ int lds_idx(int r, int dl) {
    // swizzled float index into the 1024x16 slice
    return (r << 4) + (((r >> 1) ^ dl) & 15);
}

__global__ __launch_bounds__(1024, 8) void vq_lds_gather_kernel(
    const int* __restrict__ indices,
    const float* __restrict__ embedding,
    float* __restrict__ out)
{
    __shared__ float lds[1024 * DC];   // 64 KiB exactly

    const int b  = blockIdx.x >> 4;        // 0..31
    const int d0 = (blockIdx.x & 15) * DC; // 0,16,..,240
    const int t  = threadIdx.x;

    // ---- Phase 1: stage embedding[:, d0:d0+16] into swizzled LDS ----
    {
        const int k  = t & 3;   // which float4 of the 16-wide row slice
        const int r0 = t >> 2;  // 0..255
        #pragma unroll
        for (int i = 0; i < 4; ++i) {
            const int r = r0 + i * 256;   // 0..1023
            const float4 v = *(const float4*)(embedding + r * VQ_D + d0 + k * 4);
            const int dl = k * 4;
            lds[lds_idx(r, dl + 0)] = v.x;
            lds[lds_idx(r, dl + 1)] = v.y;
            lds[lds_idx(r, dl + 2)] = v.z;
            lds[lds_idx(r, dl + 3)] = v.w;
        }
    }
    __syncthreads();

    // ---- Phase 2: wave w emits the full 16 KiB row out[b][d0+w][:] ----
    const int w  = t >> 6;   // wave id 0..15  <-> d within chunk
    const int l  = t & 63;   // lane           <-> n within 256-chunk (x4)
    const int dd = w;

    const int4* __restrict__ idx4 = (const int4*)(indices + b * VQ_N);
    float* __restrict__ orow = out + b * (VQ_D * VQ_N) + (d0 + w) * VQ_N;

    #pragma unroll 4
    for (int c = 0; c < VQ_N / 256; ++c) {      // 16 chunks of 256 n
        const int4 id = idx4[c * 64 + l];       // 4 consecutive n's indices
        float4 v;
        v.x = lds[lds_idx(id.x, dd)];
        v.y = lds[lds_idx(id.y, dd)];
        v.z = lds[lds_idx(id.z, dd)];
        v.w = lds[lds_idx(id.w, dd)];
        *(float4*)(orow + c * 256 + l * 4) = v; // 1 KiB contiguous per wave-instr
    }
}

extern "C" void kernel_launch(void* const* d_in, const int* in_sizes, int n_in,
                              void* d_out, int out_size, void* d_ws, size_t ws_size,
                              hipStream_t stream) {
    const int*   indices   = (const int*)d_in[0];    // (32,1,4096)
    const float* embedding = (const float*)d_in[1];  // (1024,256) fp32
    // d_in[2], d_in[3] are h=64, w=64 scalars (compile-time here)
    float* out = (float*)d_out;                      // (32,256,64,64) fp32

    vq_lds_gather_kernel<<<dim3(VQ_B * (VQ_D / DC)), dim3(1024), 0, stream>>>(
        indices, embedding, out);
}

// Round 4
// 161.137 us; speedup vs baseline: 1.0298x; 1.0298x over previous
//
#include <hip/hip_runtime.h>

// VectorQuantizer gather: out[b][d][n] = embedding[indices[b][n]][d]
// B=32, N=4096, K=1024, D=256, fp32 out = 128 MiB -> write-BW bound (~20us floor).
//
// R1 (global float4 gather + scalar stores): ~62us kernel. R2 (LDS gather): ~85us,
// reverted. Both ~3x off the 6.6 TB/s the harness fill achieves. Two theories:
//  T1: streaming stores write-allocate through 32MiB L2, evict embedding, gathers
//      escalate to L3/HBM latency.  -> attack: __builtin_nontemporal_store.
//  T2: TA serialization (64-line gathers ~64cyc each + store issue).
//      -> attack: halve store instrs (float2 along n, 512B/wave-instr).
//
// DIAGNOSTIC: rep=4 idempotent loop (re-gather forced by runtime zero_off) makes
// this dispatch ~4xK > 81us poison fills -> top-1 in rocprof with FETCH/WRITE.
//  FETCH_SIZE small (<50MB) => T2; large (>300MB) => T1 confirmed.
//
// Structure: 1024 blocks x 512 threads (4 blocks/CU, 32 waves/CU).
//  block <-> (b, 128-n tile); lane l <-> n-pair (n0+2l, +1); wave w: d-chunks 8i+w
//  (waves 0-3 share 64B line 2i of each row, waves 4-7 line 2i+1 -> L1 reuse x4).
//  Per thread: 2 embedding rows; per iter: 2 float4 gathers, 4 nt float2 stores.
//
// R3 fix: __builtin_nontemporal_store needs native vector types, not
// HIP_vector_type -> use ext_vector_type(2) float.

#define VQ_B 32
#define VQ_N 4096
#define VQ_D 256

typedef float vf2 __attribute__((ext_vector_type(2)));

__global__ __launch_bounds__(512, 8) void vq_gather2_kernel(
    const int* __restrict__ indices,
    const float* __restrict__ embedding,
    float* __restrict__ out,
    int reps, int zero_off)
{
    const int b  = blockIdx.x >> 5;          // 0..31
    const int n0 = (blockIdx.x & 31) << 7;   // 128-n tile base
    const int t  = threadIdx.x;
    const int w  = t >> 6;                   // wave 0..7 -> d-chunk phase
    const int l  = t & 63;                   // lane -> n-pair

    const int nA = n0 + 2 * l;
    const int2 id2 = *(const int2*)(indices + b * VQ_N + nA);

    const float* __restrict__ rowA = embedding + id2.x * VQ_D;
    const float* __restrict__ rowB = embedding + id2.y * VQ_D;

    float* __restrict__ outb = out + b * (VQ_D * VQ_N) + n0 + 2 * l;

    for (int r = 0; r < reps; ++r) {
        // zero_off==0 at runtime; opaque to compiler so each rep re-gathers.
        const float4* __restrict__ rA = (const float4*)(rowA + r * zero_off);
        const float4* __restrict__ rB = (const float4*)(rowB + r * zero_off);
        #pragma unroll
        for (int i = 0; i < 8; ++i) {
            const int c = i * 8 + w;         // float4 chunk 0..63 of the row
            const float4 va = rA[c];
            const float4 vb = rB[c];
            const int d = c << 2;
            vf2 s0 = {va.x, vb.x};
            vf2 s1 = {va.y, vb.y};
            vf2 s2 = {va.z, vb.z};
            vf2 s3 = {va.w, vb.w};
            __builtin_nontemporal_store(s0, (vf2*)(outb + (d + 0) * VQ_N));
            __builtin_nontemporal_store(s1, (vf2*)(outb + (d + 1) * VQ_N));
            __builtin_nontemporal_store(s2, (vf2*)(outb + (d + 2) * VQ_N));
            __builtin_nontemporal_store(s3, (vf2*)(outb + (d + 3) * VQ_N));
        }
    }
}

extern "C" void kernel_launch(void* const* d_in, const int* in_sizes, int n_in,
                              void* d_out, int out_size, void* d_ws, size_t ws_size,
                              hipStream_t stream) {
    const int*   indices   = (const int*)d_in[0];    // (32,1,4096) int32
    const float* embedding = (const float*)d_in[1];  // (1024,256) fp32
    float* out = (float*)d_out;                      // (32,256,64,64) fp32

    // DIAGNOSTIC reps=4 (idempotent re-writes; drop to 1 next round).
    vq_gather2_kernel<<<dim3(VQ_B * (VQ_N / 128)), dim3(512), 0, stream>>>(
        indices, embedding, out, 4, 0);
}